// Round 1
// 286.702 us; speedup vs baseline: 1.0052x; 1.0052x over previous
//
#include <hip/hip_runtime.h>
#include <math.h>

#define BATCH 2
#define SEQ   2048
#define NH    32
#define HID   2048
#define CHUNK 256
#define NCH   8
#define NBCH  (BATCH*NCH*NH)   // 512
#define PST   72               // padded bf16 LDS leading dim (b128-alignable)
#define BK    256
#define APST  264              // BK+8 shorts; row stride 528 B = 33*16 (b128-aligned)
#define KSPLIT 4
#define KSEG  (HID / KSPLIT)   // 512

typedef __attribute__((ext_vector_type(4))) float f32x4;
typedef __attribute__((ext_vector_type(8))) short bf16x8;
typedef unsigned int uint;
typedef unsigned short ushort;

__device__ __forceinline__ float softplusf(float x) {
    return x > 20.f ? x : log1pf(expf(x));
}

__device__ __forceinline__ short f2bf(float f) {
    union { float f; uint u; } v; v.f = f;
    uint r = v.u + 0x7FFF + ((v.u >> 16) & 1);
    return (short)(r >> 16);
}
__device__ __forceinline__ float bf2f(ushort s) {
    union { uint u; float f; } v; v.u = ((uint)s) << 16; return v.f;
}
__device__ __forceinline__ uint packbf2(float lo, float hi) {
    return (uint)(ushort)f2bf(lo) | ((uint)(ushort)f2bf(hi) << 16);
}

struct BF8 { union { bf16x8 v; short s[8]; }; };

__device__ __forceinline__ bf16x8 load_cvt8(const float* p, float scale) {
    float4 a = *(const float4*)p;
    float4 b = *(const float4*)(p + 4);
    BF8 r;
    r.s[0]=f2bf(a.x*scale); r.s[1]=f2bf(a.y*scale); r.s[2]=f2bf(a.z*scale); r.s[3]=f2bf(a.w*scale);
    r.s[4]=f2bf(b.x*scale); r.s[5]=f2bf(b.y*scale); r.s[6]=f2bf(b.z*scale); r.s[7]=f2bf(b.w*scale);
    return r.v;
}

#define MFMA(a,b,c) __builtin_amdgcn_mfma_f32_16x16x32_bf16((a),(b),(c),0,0,0)

// ---------------------------------------------------------------------------
// K1: dt/g projections as bf16 MFMA GEMM — split-K by 4 for occupancy.
// Grid = 2(which) * 128(row-tiles of 32) * 4(K-segments of 512) = 1024 blocks
// (vs 256 before: 1 block/CU with a serial 8-iter K-loop was latency-bound,
//  888 GB/s / 9.5% occupancy). LDS 33 KB -> 4 blocks/CU resident.
// Partials (f32) go to ws; k_proj_fin sums 4 partials + bias + softplus.
// ---------------------------------------------------------------------------
__global__ __launch_bounds__(256) void k_proj(
    const float* __restrict__ hs_ab, const float* __restrict__ hs_g,
    const float* __restrict__ dt_w, const float* __restrict__ g_w,
    float* __restrict__ part)
{
    __shared__ short As[32 * APST];
    __shared__ short Bs[32 * APST];
    int blk = blockIdx.x;
    int ksp = blk >> 8;          // 0..3 : K segment
    int rem = blk & 255;
    int which = rem >> 7;        // 0..1 : ab vs g
    int rt = rem & 127;          // 0..127 : 32-row tile
    int r0 = rt * 32;
    const float* Am = which ? hs_g : hs_ab;
    const float* W  = which ? g_w  : dt_w;
    int t = threadIdx.x;
    int w = t >> 6, lane = t & 63, quad = lane >> 4, l16 = lane & 15;
    int mh = w & 1, nh = w >> 1;

    f32x4 acc = (f32x4){0.f, 0.f, 0.f, 0.f};

    for (int kc = ksp * KSEG; kc < ksp * KSEG + KSEG; kc += BK) {
        __syncthreads();
        {   // stage A: 32 rows x BK cols, bf16-packed
            int row = t >> 3, k0 = (t & 7) * 32;
            const float* src = Am + (size_t)(r0 + row) * HID + kc + k0;
            uint* dst = (uint*)(As + row * APST + k0);
            #pragma unroll
            for (int i = 0; i < 4; ++i) {
                float4 a = *(const float4*)(src + i * 8);
                float4 b = *(const float4*)(src + i * 8 + 4);
                dst[i*4+0] = packbf2(a.x, a.y); dst[i*4+1] = packbf2(a.z, a.w);
                dst[i*4+2] = packbf2(b.x, b.y); dst[i*4+3] = packbf2(b.z, b.w);
            }
        }
        if (t < 128) {   // stage W transposed: Bs[n][k] = W[kc+k][n], pair-packed
            int k2 = t * 2;
            const float* w0 = W + (size_t)(kc + k2) * NH;
            const float* w1 = w0 + NH;
            #pragma unroll
            for (int n = 0; n < 32; n += 4) {
                float4 a = *(const float4*)(w0 + n);
                float4 b = *(const float4*)(w1 + n);
                *((uint*)(Bs + (n+0) * APST + k2)) = packbf2(a.x, b.x);
                *((uint*)(Bs + (n+1) * APST + k2)) = packbf2(a.y, b.y);
                *((uint*)(Bs + (n+2) * APST + k2)) = packbf2(a.z, b.z);
                *((uint*)(Bs + (n+3) * APST + k2)) = packbf2(a.w, b.w);
            }
        }
        __syncthreads();
        #pragma unroll
        for (int ks = 0; ks < BK / 32; ++ks) {
            bf16x8 af = *(const bf16x8*)(As + (mh*16 + l16) * APST + ks*32 + quad*8);
            bf16x8 bf = *(const bf16x8*)(Bs + (nh*16 + l16) * APST + ks*32 + quad*8);
            acc = MFMA(af, bf, acc);
        }
    }

    int n = nh * 16 + l16;
    int Rb = r0 + mh * 16 + quad * 4;
    float* pd = part + ((size_t)(which * KSPLIT + ksp) * 4096 + Rb) * 32 + n;
    #pragma unroll
    for (int r = 0; r < 4; ++r)
        pd[r * 32] = acc[r];
}

// K1b: sum split-K partials, add bias, softplus for dt.
__global__ __launch_bounds__(256) void k_proj_fin(
    const float* __restrict__ part,
    const float* __restrict__ dt_b, const float* __restrict__ g_b,
    const float* __restrict__ dt_bias,
    float* __restrict__ dt_out, float* __restrict__ g_out)
{
    int id = blockIdx.x * 256 + threadIdx.x;     // 0 .. 262143
    int which = id >> 17;                        // uniform per block
    int rid = id & 131071;                       // row*32 + n
    int n = rid & 31;
    const float* p = part + (size_t)which * (KSPLIT * 131072) + rid;
    float s = p[0] + p[131072] + p[262144] + p[393216];
    if (which == 0)
        dt_out[rid] = softplusf(s + dt_b[n] + dt_bias[n]);
    else
        g_out[rid] = s + g_b[n];
}

// ---------------------------------------------------------------------------
// K2: inverse L2 norms
// ---------------------------------------------------------------------------
__global__ __launch_bounds__(256) void k_norms(
    const float* __restrict__ q, const float* __restrict__ k,
    float* __restrict__ invC, float* __restrict__ invB)
{
    int t = threadIdx.x;
    int lane = t & 63;
    size_t row = (size_t)blockIdx.x * 4 + (t >> 6);
    float qv = q[row * 64 + lane];
    float kv = k[row * 64 + lane];
    float sq = qv * qv, sk = kv * kv;
    #pragma unroll
    for (int off = 32; off > 0; off >>= 1) {
        sq += __shfl_down(sq, off);
        sk += __shfl_down(sk, off);
    }
    if (lane == 0) {
        invC[row] = 1.f / fmaxf(sqrtf(sq), 1e-12f);
        invB[row] = 1.f / fmaxf(sqrtf(sk), 1e-12f);
    }
}

// ---------------------------------------------------------------------------
// K3: per (b,c,h) cumsum of dt*A; chunk-ordered cum/dt/w; chunk decay
// ---------------------------------------------------------------------------
__global__ __launch_bounds__(256) void k_cumsum(
    const float* __restrict__ dt, const float* __restrict__ A_log,
    float* __restrict__ cumc, float* __restrict__ wvc,
    float* __restrict__ dtc, float* __restrict__ cd)
{
    __shared__ float sC[256];
    int bch = blockIdx.x;
    int h = bch & 31, c = (bch >> 5) & 7, b = bch >> 8;
    int t = threadIdx.x;
    size_t row = ((size_t)b * SEQ + c * CHUNK + t) * NH + h;
    float dt_l = dt[row];
    float A = -expf(A_log[h]);
    sC[t] = dt_l * A;
    __syncthreads();
    for (int off = 1; off < 256; off <<= 1) {
        float v = (t >= off) ? sC[t - off] : 0.f;
        __syncthreads();
        sC[t] += v;
        __syncthreads();
    }
    float cum = sC[t], cl = sC[255];
    size_t o = (size_t)bch * CHUNK + t;
    cumc[o] = cum;
    wvc[o] = expf(cl - cum) * dt_l;
    dtc[o] = dt_l;
    if (t == 255) cd[bch] = expf(cl);
}

// ---------------------------------------------------------------------------
// K4: partial chunk states
// ---------------------------------------------------------------------------
__global__ __launch_bounds__(256) void k_states(
    const float* __restrict__ kst, const float* __restrict__ vst,
    const float* __restrict__ invB, const float* __restrict__ wvc,
    float* __restrict__ sp)
{
    __shared__ float kS[64 * 64];
    __shared__ float xS[64 * 64];
    int blk = blockIdx.x;
    int half = blk & 1, bch = blk >> 1;
    int h = bch & 31, c = (bch >> 5) & 7, b = bch >> 8;
    int t = threadIdx.x;
    size_t rowbase = (size_t)b * SEQ + c * CHUNK + half * 128;
    int pg = (t & 15) * 4, ng = (t >> 4) * 4;
    float acc[4][4];
    #pragma unroll
    for (int i = 0; i < 4; ++i)
        #pragma unroll
        for (int j = 0; j < 4; ++j) acc[i][j] = 0.f;

    for (int tt = 0; tt < 2; ++tt) {
        int r0 = t >> 4;
        int c4 = (t & 15) * 4;
        #pragma unroll
        for (int i = 0; i < 4; ++i) {
            int row = r0 + i * 16;
            size_t grow = (rowbase + tt * 64 + row) * NH + h;
            float w  = wvc[(size_t)bch * CHUNK + half * 128 + tt * 64 + row];
            float ib = invB[grow];
            float4 kv = *(const float4*)(kst + grow * 64 + c4);
            float4 xv = *(const float4*)(vst + grow * 64 + c4);
            *(float4*)(kS + row * 64 + c4) =
                make_float4(kv.x * ib, kv.y * ib, kv.z * ib, kv.w * ib);
            *(float4*)(xS + row * 64 + c4) =
                make_float4(xv.x * w, xv.y * w, xv.z * w, xv.w * w);
        }
        __syncthreads();
        for (int ll = 0; ll < 64; ++ll) {
            float4 x4 = *(const float4*)(xS + ll * 64 + pg);
            float4 k4 = *(const float4*)(kS + ll * 64 + ng);
            acc[0][0] += x4.x * k4.x; acc[0][1] += x4.x * k4.y;
            acc[0][2] += x4.x * k4.z; acc[0][3] += x4.x * k4.w;
            acc[1][0] += x4.y * k4.x; acc[1][1] += x4.y * k4.y;
            acc[1][2] += x4.y * k4.z; acc[1][3] += x4.y * k4.w;
            acc[2][0] += x4.z * k4.x; acc[2][1] += x4.z * k4.y;
            acc[2][2] += x4.z * k4.z; acc[2][3] += x4.z * k4.w;
            acc[3][0] += x4.w * k4.x; acc[3][1] += x4.w * k4.y;
            acc[3][2] += x4.w * k4.z; acc[3][3] += x4.w * k4.w;
        }
        __syncthreads();
    }
    size_t obase = (size_t)blk * 4096;
    #pragma unroll
    for (int i = 0; i < 4; ++i)
        *(float4*)(sp + obase + (pg + i) * 64 + ng) =
            make_float4(acc[i][0], acc[i][1], acc[i][2], acc[i][3]);
}

// ---------------------------------------------------------------------------
// K5: inter-chunk scan
// ---------------------------------------------------------------------------
__global__ __launch_bounds__(256) void k_scan(
    const float* __restrict__ sp, const float* __restrict__ cd,
    float* __restrict__ Hp)
{
    size_t id = (size_t)blockIdx.x * 256 + threadIdx.x;
    size_t bh = id >> 12, pn = id & 4095;
    size_t b = bh >> 5, h = bh & 31;
    float carry = 0.f;
    for (int c = 0; c < NCH; ++c) {
        size_t bch = (b * NCH + c) * NH + h;
        float st = sp[(bch * 2) * 4096 + pn] + sp[(bch * 2 + 1) * 4096 + pn];
        Hp[bch * 4096 + pn] = carry;
        carry = cd[bch] * carry + st;
    }
}

// ---------------------------------------------------------------------------
// K6: MFMA intra-chunk + H_prev (unchanged from R3)
// ---------------------------------------------------------------------------
__global__ __launch_bounds__(256, 2) void k_intra(
    const float* __restrict__ qst, const float* __restrict__ kst,
    const float* __restrict__ vst,
    const float* __restrict__ invC, const float* __restrict__ invB,
    const float* __restrict__ cumc, const float* __restrict__ dtc,
    const float* __restrict__ Hp,
    short* __restrict__ ygb)
{
    __shared__ short B_s[64 * PST];
    __shared__ short XT_s[64 * PST];
    __shared__ short P_s[4 * 32 * PST];
    __shared__ float sCum[256];
    __shared__ float sDt[256];

    int bch = blockIdx.x;
    int h = bch & 31, c = (bch >> 5) & 7, b = bch >> 8;
    int t = threadIdx.x;
    int w = t >> 6, lane = t & 63;
    int quad = lane >> 4, l16 = lane & 15;
    size_t rowbase = (size_t)b * SEQ + c * CHUNK;

    sCum[t] = cumc[(size_t)bch * CHUNK + t];
    sDt[t]  = dtc[(size_t)bch * CHUNK + t];
    __syncthreads();

    bf16x8 cf[2][2][2];
    #pragma unroll
    for (int is = 0; is < 2; ++is) {
        int strip = is ? (7 - w) : w;
        #pragma unroll
        for (int lt = 0; lt < 2; ++lt) {
            int l = strip * 32 + lt * 16 + l16;
            size_t grow = (rowbase + l) * NH + h;
            float ic = invC[grow];
            const float* qp = qst + grow * 64 + quad * 8;
            cf[is][lt][0] = load_cvt8(qp, ic);
            cf[is][lt][1] = load_cvt8(qp + 32, ic);
        }
    }

    f32x4 acc[2][2][4];
    #pragma unroll
    for (int is = 0; is < 2; ++is)
        #pragma unroll
        for (int lt = 0; lt < 2; ++lt)
            #pragma unroll
            for (int pt = 0; pt < 4; ++pt)
                acc[is][lt][pt] = (f32x4){0.f, 0.f, 0.f, 0.f};

    {
        bf16x8 hf[4][2];
        #pragma unroll
        for (int pt = 0; pt < 4; ++pt) {
            const float* hp = Hp + (size_t)bch * 4096 + (pt * 16 + l16) * 64 + quad * 8;
            hf[pt][0] = load_cvt8(hp, 1.f);
            hf[pt][1] = load_cvt8(hp + 32, 1.f);
        }
        #pragma unroll
        for (int is = 0; is < 2; ++is)
            #pragma unroll
            for (int lt = 0; lt < 2; ++lt)
                #pragma unroll
                for (int pt = 0; pt < 4; ++pt) {
                    acc[is][lt][pt] = MFMA(cf[is][lt][0], hf[pt][0], acc[is][lt][pt]);
                    acc[is][lt][pt] = MFMA(cf[is][lt][1], hf[pt][1], acc[is][lt][pt]);
                }
    }
    #pragma unroll
    for (int is = 0; is < 2; ++is) {
        int strip = is ? (7 - w) : w;
        #pragma unroll
        for (int lt = 0; lt < 2; ++lt) {
            float e[4];
            #pragma unroll
            for (int r = 0; r < 4; ++r)
                e[r] = __expf(sCum[strip * 32 + lt * 16 + quad * 4 + r]);
            #pragma unroll
            for (int pt = 0; pt < 4; ++pt)
                #pragma unroll
                for (int r = 0; r < 4; ++r)
                    acc[is][lt][pt][r] *= e[r];
        }
    }

    short* Pw = P_s + w * 32 * PST;

    for (int st = 0; st < 4; ++st) {
        __syncthreads();
        {
            int ss = t >> 2, q4 = (t & 3) * 16;
            size_t grow = (rowbase + st * 64 + ss) * NH + h;
            float ib = invB[grow];
            const float4* kp = (const float4*)(kst + grow * 64 + q4);
            float4 v0 = kp[0], v1 = kp[1], v2 = kp[2], v3 = kp[3];
            uint u[8];
            u[0] = packbf2(v0.x * ib, v0.y * ib); u[1] = packbf2(v0.z * ib, v0.w * ib);
            u[2] = packbf2(v1.x * ib, v1.y * ib); u[3] = packbf2(v1.z * ib, v1.w * ib);
            u[4] = packbf2(v2.x * ib, v2.y * ib); u[5] = packbf2(v2.z * ib, v2.w * ib);
            u[6] = packbf2(v3.x * ib, v3.y * ib); u[7] = packbf2(v3.z * ib, v3.w * ib);
            uint* dst = (uint*)(B_s + ss * PST + q4);
            *(uint4*)dst = make_uint4(u[0], u[1], u[2], u[3]);
            *(uint4*)(dst + 4) = make_uint4(u[4], u[5], u[6], u[7]);
        }
        {
            int ss2 = t & 31, qh = t >> 5;
            int p0 = qh * 8;
            size_t g0 = (rowbase + st * 64 + 2 * ss2) * NH + h;
            size_t g1 = g0 + NH;
            float dt0 = sDt[st * 64 + 2 * ss2];
            float dt1 = sDt[st * 64 + 2 * ss2 + 1];
            float4 a0 = *(const float4*)(vst + g0 * 64 + p0);
            float4 a1 = *(const float4*)(vst + g0 * 64 + p0 + 4);
            float4 b0 = *(const float4*)(vst + g1 * 64 + p0);
            float4 b1 = *(const float4*)(vst + g1 * 64 + p0 + 4);
            float x0[8] = {a0.x, a0.y, a0.z, a0.w, a1.x, a1.y, a1.z, a1.w};
            float x1[8] = {b0.x, b0.y, b0.z, b0.w, b1.x, b1.y, b1.z, b1.w};
            uint* xt = (uint*)XT_s;
            #pragma unroll
            for (int i = 0; i < 8; ++i)
                xt[(p0 + i) * (PST / 2) + ss2] = packbf2(x0[i] * dt0, x1[i] * dt1);
        }
        __syncthreads();

        bf16x8 xf[4][2];
        #pragma unroll
        for (int pt = 0; pt < 4; ++pt) {
            #pragma unroll
            for (int ks = 0; ks < 2; ++ks)
                xf[pt][ks] = *(const bf16x8*)(XT_s + (pt * 16 + l16) * PST + ks * 32 + quad * 8);
        }

        #pragma unroll
        for (int is = 0; is < 2; ++is) {
            int strip = is ? (7 - w) : w;
            int L0 = strip * 32;
            if (L0 + 31 < st * 64) continue;

            #pragma unroll
            for (int lt = 0; lt < 2; ++lt) {
                int Lt = L0 + lt * 16;
                float cl = sCum[Lt + l16];
                int lrow = lt * 16 + l16;
                #pragma unroll
                for (int mt = 0; mt < 4; ++mt) {
                    int S0 = st * 64 + mt * 16;
                    uint* pdst = (uint*)(Pw + lrow * PST + mt * 16 + quad * 4);
                    if (S0 > Lt + 15) {
                        *(uint2*)pdst = make_uint2(0u, 0u);
                        continue;
                    }
                    f32x4 sa = (f32x4){0.f, 0.f, 0.f, 0.f};
                    bf16x8 af0 = *(const bf16x8*)(B_s + (mt * 16 + l16) * PST + quad * 8);
                    bf16x8 af1 = *(const bf16x8*)(B_s + (mt * 16 + l16) * PST + 32 + quad * 8);
                    sa = MFMA(af0, cf[is][lt][0], sa);
                    sa = MFMA(af1, cf[is][lt][1], sa);
                    float vals[4];
                    #pragma unroll
                    for (int r = 0; r < 4; ++r) {
                        int s = S0 + quad * 4 + r;
                        float v = sa[r] * __expf(cl - sCum[s]);
                        vals[r] = (Lt + l16 >= s) ? v : 0.f;
                    }
                    *(uint2*)pdst = make_uint2(packbf2(vals[0], vals[1]),
                                               packbf2(vals[2], vals[3]));
                }
            }
            #pragma unroll
            for (int lt = 0; lt < 2; ++lt) {
                int Lmax = L0 + lt * 16 + 15;
                #pragma unroll
                for (int ks = 0; ks < 2; ++ks) {
                    if (st * 64 + ks * 32 > Lmax) continue;
                    bf16x8 af = *(const bf16x8*)(Pw + (lt * 16 + l16) * PST + ks * 32 + quad * 8);
                    #pragma unroll
                    for (int pt = 0; pt < 4; ++pt)
                        acc[is][lt][pt] = MFMA(af, xf[pt][ks], acc[is][lt][pt]);
                }
            }
        }
    }

    #pragma unroll
    for (int is = 0; is < 2; ++is) {
        int strip = is ? (7 - w) : w;
        #pragma unroll
        for (int lt = 0; lt < 2; ++lt)
            #pragma unroll
            for (int pt = 0; pt < 4; ++pt)
                #pragma unroll
                for (int r = 0; r < 4; ++r) {
                    int l = strip * 32 + lt * 16 + quad * 4 + r;
                    int p = pt * 16 + l16;
                    ygb[((rowbase + l) * NH + h) * 64 + p] = f2bf(acc[is][lt][pt][r]);
                }
    }
}

// ---------------------------------------------------------------------------
// K7: gate + RMSNorm (bf16 in/out)
// ---------------------------------------------------------------------------
__global__ __launch_bounds__(256) void k_gate(
    const short* __restrict__ ygb, const float* __restrict__ g_ws,
    const float* __restrict__ norm_w, short* __restrict__ ygn)
{
    __shared__ float sil[32];
    __shared__ float red[256];
    int r = blockIdx.x;
    int t = threadIdx.x;
    if (t < 32) {
        float g = g_ws[(size_t)r * 32 + t];
        sil[t] = g / (1.f + expf(-g));
    }
    __syncthreads();
    uint4 u = *(const uint4*)(ygb + (size_t)r * 2048 + t * 8);
    float s = sil[t >> 3];
    float v[8];
    v[0] = bf2f(u.x & 0xFFFF) * s; v[1] = bf2f(u.x >> 16) * s;
    v[2] = bf2f(u.y & 0xFFFF) * s; v[3] = bf2f(u.y >> 16) * s;
    v[4] = bf2f(u.z & 0xFFFF) * s; v[5] = bf2f(u.z >> 16) * s;
    v[6] = bf2f(u.w & 0xFFFF) * s; v[7] = bf2f(u.w >> 16) * s;
    float ssq = 0.f;
    #pragma unroll
    for (int i = 0; i < 8; ++i) ssq += v[i] * v[i];
    red[t] = ssq;
    __syncthreads();
    for (int off = 128; off > 0; off >>= 1) {
        if (t < off) red[t] += red[t + off];
        __syncthreads();
    }
    float scale = rsqrtf(red[0] / 2048.f + 1e-5f);
    const float* nw = norm_w + t * 8;
    uint4 o;
    o.x = packbf2(v[0] * scale * nw[0], v[1] * scale * nw[1]);
    o.y = packbf2(v[2] * scale * nw[2], v[3] * scale * nw[3]);
    o.z = packbf2(v[4] * scale * nw[4], v[5] * scale * nw[5]);
    o.w = packbf2(v[6] * scale * nw[6], v[7] * scale * nw[7]);
    *(uint4*)(ygn + (size_t)r * 2048 + t * 8) = o;
}

// ---------------------------------------------------------------------------
// K8: per-head o_proj via MFMA
// ---------------------------------------------------------------------------
__global__ __launch_bounds__(256) void k_oproj(
    const short* __restrict__ ygn, const float* __restrict__ o_w,
    const float* __restrict__ o_b, float* __restrict__ out)
{
    __shared__ short wT[64 * PST];
    int blk = blockIdx.x;
    int h = blk & 31, rt = blk >> 5;
    int t = threadIdx.x;
    int w = t >> 6, lane = t & 63;
    int quad = lane >> 4, l16 = lane & 15;

    {
        int p = t >> 2, q4 = (t & 3) * 16;
        const float* wp = o_w + (size_t)h * 4096 + p * 64 + q4;
        float4 v0 = *(const float4*)wp, v1 = *(const float4*)(wp + 4);
        float4 v2 = *(const float4*)(wp + 8), v3 = *(const float4*)(wp + 12);
        float vv[16] = {v0.x,v0.y,v0.z,v0.w, v1.x,v1.y,v1.z,v1.w,
                        v2.x,v2.y,v2.z,v2.w, v3.x,v3.y,v3.z,v3.w};
        #pragma unroll
        for (int i = 0; i < 16; ++i)
            wT[(q4 + i) * PST + p] = f2bf(vv[i]);
    }
    __syncthreads();

    bf16x8 bfr[4][2];
    #pragma unroll
    for (int nt = 0; nt < 4; ++nt)
        #pragma unroll
        for (int ks = 0; ks < 2; ++ks)
            bfr[nt][ks] = *(const bf16x8*)(wT + (nt * 16 + l16) * PST + ks * 32 + quad * 8);

    int rowbase = rt * 256 + w * 64;
    f32x4 acc[4][4];
    #pragma unroll
    for (int nt = 0; nt < 4; ++nt) {
        float bv = o_b[h * 64 + nt * 16 + l16];
        #pragma unroll
        for (int mt = 0; mt < 4; ++mt)
            acc[mt][nt] = (f32x4){bv, bv, bv, bv};
    }
    #pragma unroll
    for (int ks = 0; ks < 2; ++ks) {
        #pragma unroll
        for (int mt = 0; mt < 4; ++mt) {
            int row = rowbase + mt * 16 + l16;
            bf16x8 af = *(const bf16x8*)(ygn + (size_t)row * 2048 + h * 64 + ks * 32 + quad * 8);
            #pragma unroll
            for (int nt = 0; nt < 4; ++nt)
                acc[mt][nt] = MFMA(af, bfr[nt][ks], acc[mt][nt]);
        }
    }
    #pragma unroll
    for (int mt = 0; mt < 4; ++mt)
        #pragma unroll
        for (int nt = 0; nt < 4; ++nt)
            #pragma unroll
            for (int r = 0; r < 4; ++r) {
                int row = rowbase + mt * 16 + quad * 4 + r;
                out[(size_t)row * 2048 + h * 64 + nt * 16 + l16] = acc[mt][nt][r];
            }
}

extern "C" void kernel_launch(void* const* d_in, const int* in_sizes, int n_in,
                              void* d_out, int out_size, void* d_ws, size_t ws_size,
                              hipStream_t stream) {
    const float* hs_ab   = (const float*)d_in[0];
    const float* hs_g    = (const float*)d_in[1];
    const float* qst     = (const float*)d_in[2];
    const float* kst     = (const float*)d_in[3];
    const float* vst     = (const float*)d_in[4];
    const float* dt_w    = (const float*)d_in[5];
    const float* dt_b    = (const float*)d_in[6];
    const float* g_w     = (const float*)d_in[7];
    const float* g_b     = (const float*)d_in[8];
    const float* A_log   = (const float*)d_in[9];
    const float* dt_bias = (const float*)d_in[10];
    const float* norm_w  = (const float*)d_in[11];
    const float* o_w     = (const float*)d_in[12];
    const float* o_b     = (const float*)d_in[13];
    float* out = (float*)d_out;

    float* ws = (float*)d_ws;
    size_t off = 0;
    // split-K partials FIRST (so ygn's tail overflow past Hp stays clear of it)
    float* part   = ws + off; off += (size_t)2 * KSPLIT * 4096 * 32;  // 1M floats
    float* dt_ws  = ws + off; off += (size_t)BATCH * SEQ * NH;
    float* g_ws   = ws + off; off += (size_t)BATCH * SEQ * NH;
    float* invC   = ws + off; off += (size_t)BATCH * SEQ * NH;
    float* invB   = ws + off; off += (size_t)BATCH * SEQ * NH;
    float* cumc   = ws + off; off += (size_t)NBCH * CHUNK;
    float* wvc    = ws + off; off += (size_t)NBCH * CHUNK;
    float* dtc    = ws + off; off += (size_t)NBCH * CHUNK;
    float* cd_ws  = ws + off; off += (size_t)NBCH;
    float* sp     = ws + off; off += (size_t)NBCH * 2 * 4096;
    float* Hp     = ws + off; off += (size_t)NBCH * 4096;

    short* ygb = (short*)sp;
    short* ygn = (short*)sp + (size_t)BATCH * SEQ * NH * 64;

    k_proj<<<2 * KSPLIT * (BATCH * SEQ / 32), 256, 0, stream>>>(
        hs_ab, hs_g, dt_w, g_w, part);
    k_proj_fin<<<2 * BATCH * SEQ * NH / 256, 256, 0, stream>>>(
        part, dt_b, g_b, dt_bias, dt_ws, g_ws);
    k_norms<<<BATCH * SEQ * NH / 4, 256, 0, stream>>>(qst, kst, invC, invB);
    k_cumsum<<<NBCH, 256, 0, stream>>>(dt_ws, A_log, cumc, wvc, dtc, cd_ws);
    k_states<<<NBCH * 2, 256, 0, stream>>>(kst, vst, invB, wvc, sp);
    k_scan<<<BATCH * NH * 4096 / 256, 256, 0, stream>>>(sp, cd_ws, Hp);
    k_intra<<<NBCH, 256, 0, stream>>>(qst, kst, vst, invC, invB,
                                      cumc, dtc, Hp, ygb);
    k_gate<<<BATCH * SEQ, 256, 0, stream>>>(ygb, g_ws, norm_w, ygn);
    k_oproj<<<32 * (BATCH * SEQ / 256), 256, 0, stream>>>(ygn, o_w, o_b, out);
}

// Round 3
// 270.800 us; speedup vs baseline: 1.0642x; 1.0587x over previous
//
#include <hip/hip_runtime.h>
#include <math.h>

#define BATCH 2
#define SEQ   2048
#define NH    32
#define HID   2048
#define CHUNK 256
#define NCH   8
#define NBCH  (BATCH*NCH*NH)   // 512
#define PST   72               // padded bf16 LDS leading dim (b128-alignable)
#define BK    256
#define APST  264              // BK+8 shorts; row stride 528 B = 33*16 (b128-aligned)
#define KSPLIT 4
#define KSEG  (HID / KSPLIT)   // 512

typedef __attribute__((ext_vector_type(4))) float f32x4;
typedef __attribute__((ext_vector_type(8))) short bf16x8;
typedef unsigned int uint;
typedef unsigned short ushort;

__device__ __forceinline__ float softplusf(float x) {
    return x > 20.f ? x : log1pf(expf(x));
}

__device__ __forceinline__ short f2bf(float f) {
    union { float f; uint u; } v; v.f = f;
    uint r = v.u + 0x7FFF + ((v.u >> 16) & 1);
    return (short)(r >> 16);
}
__device__ __forceinline__ float bf2f(ushort s) {
    union { uint u; float f; } v; v.u = ((uint)s) << 16; return v.f;
}
__device__ __forceinline__ uint packbf2(float lo, float hi) {
    return (uint)(ushort)f2bf(lo) | ((uint)(ushort)f2bf(hi) << 16);
}

struct BF8 { union { bf16x8 v; short s[8]; }; };

__device__ __forceinline__ bf16x8 load_cvt8(const float* p, float scale) {
    float4 a = *(const float4*)p;
    float4 b = *(const float4*)(p + 4);
    BF8 r;
    r.s[0]=f2bf(a.x*scale); r.s[1]=f2bf(a.y*scale); r.s[2]=f2bf(a.z*scale); r.s[3]=f2bf(a.w*scale);
    r.s[4]=f2bf(b.x*scale); r.s[5]=f2bf(b.y*scale); r.s[6]=f2bf(b.z*scale); r.s[7]=f2bf(b.w*scale);
    return r.v;
}

__device__ __forceinline__ bf16x8 cvt8(float4 a, float4 b, float s) {
    BF8 r;
    r.s[0]=f2bf(a.x*s); r.s[1]=f2bf(a.y*s); r.s[2]=f2bf(a.z*s); r.s[3]=f2bf(a.w*s);
    r.s[4]=f2bf(b.x*s); r.s[5]=f2bf(b.y*s); r.s[6]=f2bf(b.z*s); r.s[7]=f2bf(b.w*s);
    return r.v;
}

#define MFMA(a,b,c) __builtin_amdgcn_mfma_f32_16x16x32_bf16((a),(b),(c),0,0,0)

// ---------------------------------------------------------------------------
// K1: dt/g projections as bf16 MFMA GEMM (split-K by 4), plus 32 trailing
// blocks that build nwWT[h][q][p] = bf16(o_w[h][p][q] * norm_w[h*64+p]).
// ---------------------------------------------------------------------------
__global__ __launch_bounds__(256) void k_proj(
    const float* __restrict__ hs_ab, const float* __restrict__ hs_g,
    const float* __restrict__ dt_w, const float* __restrict__ g_w,
    const float* __restrict__ o_w,  const float* __restrict__ norm_w,
    float* __restrict__ part, short* __restrict__ nwWT)
{
    __shared__ __align__(16) short As[32 * APST];
    __shared__ __align__(16) short Bs[32 * APST];
    int blk = blockIdx.x;
    int t = threadIdx.x;

    if (blk >= 2 * KSPLIT * 128) {
        // --- weight prep: transpose o_w per head, fold norm_w, cast bf16 ---
        int h = blk - 2 * KSPLIT * 128;
        float* tile = (float*)As;   // 64x64 f32 = 16 KB, fits in As (16.9 KB)
        {
            int p = t >> 2, q0 = (t & 3) * 16;
            const float* wp = o_w + (size_t)h * 4096 + p * 64 + q0;
            #pragma unroll
            for (int i = 0; i < 4; ++i)
                *(float4*)(tile + p * 64 + q0 + i * 4) = *(const float4*)(wp + i * 4);
        }
        __syncthreads();
        int q = t >> 2, p0 = (t & 3) * 16;
        uint us[8];
        #pragma unroll
        for (int j = 0; j < 8; ++j) {
            float lo = tile[(p0 + 2*j    ) * 64 + q] * norm_w[h * 64 + p0 + 2*j];
            float hi = tile[(p0 + 2*j + 1) * 64 + q] * norm_w[h * 64 + p0 + 2*j + 1];
            us[j] = packbf2(lo, hi);
        }
        uint* dst = (uint*)(nwWT + (size_t)h * 4096 + q * 64 + p0);
        *(uint4*)dst       = make_uint4(us[0], us[1], us[2], us[3]);
        *(uint4*)(dst + 4) = make_uint4(us[4], us[5], us[6], us[7]);
        return;
    }

    int ksp = blk >> 8;          // 0..3 : K segment
    int rem = blk & 255;
    int which = rem >> 7;        // 0..1 : ab vs g
    int rt = rem & 127;          // 0..127 : 32-row tile
    int r0 = rt * 32;
    const float* Am = which ? hs_g : hs_ab;
    const float* W  = which ? g_w  : dt_w;
    int w = t >> 6, lane = t & 63, quad = lane >> 4, l16 = lane & 15;
    int mh = w & 1, nh = w >> 1;

    f32x4 acc = (f32x4){0.f, 0.f, 0.f, 0.f};

    for (int kc = ksp * KSEG; kc < ksp * KSEG + KSEG; kc += BK) {
        __syncthreads();
        {   // stage A: 32 rows x BK cols, bf16-packed
            int row = t >> 3, k0 = (t & 7) * 32;
            const float* src = Am + (size_t)(r0 + row) * HID + kc + k0;
            uint* dst = (uint*)(As + row * APST + k0);
            #pragma unroll
            for (int i = 0; i < 4; ++i) {
                float4 a = *(const float4*)(src + i * 8);
                float4 b = *(const float4*)(src + i * 8 + 4);
                dst[i*4+0] = packbf2(a.x, a.y); dst[i*4+1] = packbf2(a.z, a.w);
                dst[i*4+2] = packbf2(b.x, b.y); dst[i*4+3] = packbf2(b.z, b.w);
            }
        }
        if (t < 128) {   // stage W transposed: Bs[n][k] = W[kc+k][n], pair-packed
            int k2 = t * 2;
            const float* w0 = W + (size_t)(kc + k2) * NH;
            const float* w1 = w0 + NH;
            #pragma unroll
            for (int n = 0; n < 32; n += 4) {
                float4 a = *(const float4*)(w0 + n);
                float4 b = *(const float4*)(w1 + n);
                *((uint*)(Bs + (n+0) * APST + k2)) = packbf2(a.x, b.x);
                *((uint*)(Bs + (n+1) * APST + k2)) = packbf2(a.y, b.y);
                *((uint*)(Bs + (n+2) * APST + k2)) = packbf2(a.z, b.z);
                *((uint*)(Bs + (n+3) * APST + k2)) = packbf2(a.w, b.w);
            }
        }
        __syncthreads();
        #pragma unroll
        for (int ks = 0; ks < BK / 32; ++ks) {
            bf16x8 af = *(const bf16x8*)(As + (mh*16 + l16) * APST + ks*32 + quad*8);
            bf16x8 bf = *(const bf16x8*)(Bs + (nh*16 + l16) * APST + ks*32 + quad*8);
            acc = MFMA(af, bf, acc);
        }
    }

    int n = nh * 16 + l16;
    int Rb = r0 + mh * 16 + quad * 4;
    float* pd = part + ((size_t)(which * KSPLIT + ksp) * 4096 + Rb) * 32 + n;
    #pragma unroll
    for (int r = 0; r < 4; ++r)
        pd[r * 32] = acc[r];
}

// ---------------------------------------------------------------------------
// K2: per (b,c,h): sum dt split-K partials + bias + softplus, wave-shfl scan
// of dt*A; emits chunk-ordered cum/dt/w and chunk decay.
// ---------------------------------------------------------------------------
__global__ __launch_bounds__(256) void k_cumsum(
    const float* __restrict__ part, const float* __restrict__ dt_b,
    const float* __restrict__ dt_bias, const float* __restrict__ A_log,
    float* __restrict__ cumc, float* __restrict__ wvc,
    float* __restrict__ dtc, float* __restrict__ cd)
{
    __shared__ float wsum[4];
    int bch = blockIdx.x;
    int h = bch & 31, c = (bch >> 5) & 7, b = bch >> 8;
    int t = threadIdx.x;
    int w = t >> 6, lane = t & 63;
    int rid = (b * SEQ + c * CHUNK + t) * 32 + h;
    float s = part[rid] + part[131072 + rid] + part[262144 + rid] + part[393216 + rid];
    float dt_l = softplusf(s + dt_b[h] + dt_bias[h]);
    float A = -expf(A_log[h]);
    float v = dt_l * A;
    #pragma unroll
    for (int off = 1; off < 64; off <<= 1) {
        float u = __shfl_up(v, off);
        if (lane >= off) v += u;
    }
    if (lane == 63) wsum[w] = v;
    __syncthreads();
    float pre = 0.f;
    #pragma unroll
    for (int i = 0; i < 3; ++i)
        if (i < w) pre += wsum[i];
    float cum = v + pre;
    float tot = wsum[0] + wsum[1] + wsum[2] + wsum[3];
    size_t o = (size_t)bch * CHUNK + t;
    cumc[o] = cum;
    wvc[o] = expf(tot - cum) * dt_l;
    dtc[o] = dt_l;
    if (t == 255) cd[bch] = expf(tot);
}

// ---------------------------------------------------------------------------
// K4: partial chunk states (invB computed inline: 4-elem sumsq + shfl over
// the 16 lanes that hold the row)
// ---------------------------------------------------------------------------
__global__ __launch_bounds__(256) void k_states(
    const float* __restrict__ kst, const float* __restrict__ vst,
    const float* __restrict__ wvc, float* __restrict__ sp)
{
    __shared__ __align__(16) float kS[64 * 64];
    __shared__ __align__(16) float xS[64 * 64];
    int blk = blockIdx.x;
    int half = blk & 1, bch = blk >> 1;
    int h = bch & 31, c = (bch >> 5) & 7, b = bch >> 8;
    int t = threadIdx.x;
    size_t rowbase = (size_t)b * SEQ + c * CHUNK + half * 128;
    int pg = (t & 15) * 4, ng = (t >> 4) * 4;
    float acc[4][4];
    #pragma unroll
    for (int i = 0; i < 4; ++i)
        #pragma unroll
        for (int j = 0; j < 4; ++j) acc[i][j] = 0.f;

    for (int tt = 0; tt < 2; ++tt) {
        int r0 = t >> 4;
        int c4 = (t & 15) * 4;
        #pragma unroll
        for (int i = 0; i < 4; ++i) {
            int row = r0 + i * 16;
            size_t grow = (rowbase + tt * 64 + row) * NH + h;
            float wv = wvc[(size_t)bch * CHUNK + half * 128 + tt * 64 + row];
            float4 kv = *(const float4*)(kst + grow * 64 + c4);
            float4 xv = *(const float4*)(vst + grow * 64 + c4);
            float ssq = kv.x*kv.x + kv.y*kv.y + kv.z*kv.z + kv.w*kv.w;
            ssq += __shfl_xor(ssq, 1); ssq += __shfl_xor(ssq, 2);
            ssq += __shfl_xor(ssq, 4); ssq += __shfl_xor(ssq, 8);
            float ib = 1.f / fmaxf(sqrtf(ssq), 1e-12f);
            *(float4*)(kS + row * 64 + c4) =
                make_float4(kv.x * ib, kv.y * ib, kv.z * ib, kv.w * ib);
            *(float4*)(xS + row * 64 + c4) =
                make_float4(xv.x * wv, xv.y * wv, xv.z * wv, xv.w * wv);
        }
        __syncthreads();
        for (int ll = 0; ll < 64; ++ll) {
            float4 x4 = *(const float4*)(xS + ll * 64 + pg);
            float4 k4 = *(const float4*)(kS + ll * 64 + ng);
            acc[0][0] += x4.x * k4.x; acc[0][1] += x4.x * k4.y;
            acc[0][2] += x4.x * k4.z; acc[0][3] += x4.x * k4.w;
            acc[1][0] += x4.y * k4.x; acc[1][1] += x4.y * k4.y;
            acc[1][2] += x4.y * k4.z; acc[1][3] += x4.y * k4.w;
            acc[2][0] += x4.z * k4.x; acc[2][1] += x4.z * k4.y;
            acc[2][2] += x4.z * k4.z; acc[2][3] += x4.z * k4.w;
            acc[3][0] += x4.w * k4.x; acc[3][1] += x4.w * k4.y;
            acc[3][2] += x4.w * k4.z; acc[3][3] += x4.w * k4.w;
        }
        __syncthreads();
    }
    size_t obase = (size_t)blk * 4096;
    #pragma unroll
    for (int i = 0; i < 4; ++i)
        *(float4*)(sp + obase + (pg + i) * 64 + ng) =
            make_float4(acc[i][0], acc[i][1], acc[i][2], acc[i][3]);
}

// ---------------------------------------------------------------------------
// K5: inter-chunk scan
// ---------------------------------------------------------------------------
__global__ __launch_bounds__(256) void k_scan(
    const float* __restrict__ sp, const float* __restrict__ cd,
    float* __restrict__ Hp)
{
    size_t id = (size_t)blockIdx.x * 256 + threadIdx.x;
    size_t bh = id >> 12, pn = id & 4095;
    size_t b = bh >> 5, h = bh & 31;
    float carry = 0.f;
    for (int c = 0; c < NCH; ++c) {
        size_t bch = (b * NCH + c) * NH + h;
        float st = sp[(bch * 2) * 4096 + pn] + sp[(bch * 2 + 1) * 4096 + pn];
        Hp[bch * 4096 + pn] = carry;
        carry = cd[bch] * carry + st;
    }
}

// ---------------------------------------------------------------------------
// K6: MFMA intra-chunk + H_prev; invC/invB computed inline from the rows the
// kernel already loads (in-lane sumsq + shfl_xor across the lanes holding
// the row).
// ---------------------------------------------------------------------------
__global__ __launch_bounds__(256, 2) void k_intra(
    const float* __restrict__ qst, const float* __restrict__ kst,
    const float* __restrict__ vst,
    const float* __restrict__ cumc, const float* __restrict__ dtc,
    const float* __restrict__ Hp,
    short* __restrict__ ygb)
{
    __shared__ __align__(16) short B_s[64 * PST];
    __shared__ __align__(16) short XT_s[64 * PST];
    __shared__ __align__(16) short P_s[4 * 32 * PST];
    __shared__ float sCum[256];
    __shared__ float sDt[256];

    int bch = blockIdx.x;
    int h = bch & 31, c = (bch >> 5) & 7, b = bch >> 8;
    int t = threadIdx.x;
    int w = t >> 6, lane = t & 63;
    int quad = lane >> 4, l16 = lane & 15;
    size_t rowbase = (size_t)b * SEQ + c * CHUNK;

    sCum[t] = cumc[(size_t)bch * CHUNK + t];
    sDt[t]  = dtc[(size_t)bch * CHUNK + t];
    __syncthreads();

    bf16x8 cf[2][2][2];
    #pragma unroll
    for (int is = 0; is < 2; ++is) {
        int strip = is ? (7 - w) : w;
        #pragma unroll
        for (int lt = 0; lt < 2; ++lt) {
            int l = strip * 32 + lt * 16 + l16;
            size_t grow = (rowbase + l) * NH + h;
            const float* qp = qst + grow * 64 + quad * 8;
            float4 a  = *(const float4*)qp;
            float4 bq = *(const float4*)(qp + 4);
            float4 c2 = *(const float4*)(qp + 32);
            float4 d  = *(const float4*)(qp + 36);
            float ssq = a.x*a.x + a.y*a.y + a.z*a.z + a.w*a.w
                      + bq.x*bq.x + bq.y*bq.y + bq.z*bq.z + bq.w*bq.w
                      + c2.x*c2.x + c2.y*c2.y + c2.z*c2.z + c2.w*c2.w
                      + d.x*d.x + d.y*d.y + d.z*d.z + d.w*d.w;
            ssq += __shfl_xor(ssq, 16);
            ssq += __shfl_xor(ssq, 32);
            float ic = 1.f / fmaxf(sqrtf(ssq), 1e-12f);
            cf[is][lt][0] = cvt8(a, bq, ic);
            cf[is][lt][1] = cvt8(c2, d, ic);
        }
    }

    f32x4 acc[2][2][4];
    #pragma unroll
    for (int is = 0; is < 2; ++is)
        #pragma unroll
        for (int lt = 0; lt < 2; ++lt)
            #pragma unroll
            for (int pt = 0; pt < 4; ++pt)
                acc[is][lt][pt] = (f32x4){0.f, 0.f, 0.f, 0.f};

    {
        bf16x8 hf[4][2];
        #pragma unroll
        for (int pt = 0; pt < 4; ++pt) {
            const float* hp = Hp + (size_t)bch * 4096 + (pt * 16 + l16) * 64 + quad * 8;
            hf[pt][0] = load_cvt8(hp, 1.f);
            hf[pt][1] = load_cvt8(hp + 32, 1.f);
        }
        #pragma unroll
        for (int is = 0; is < 2; ++is)
            #pragma unroll
            for (int lt = 0; lt < 2; ++lt)
                #pragma unroll
                for (int pt = 0; pt < 4; ++pt) {
                    acc[is][lt][pt] = MFMA(cf[is][lt][0], hf[pt][0], acc[is][lt][pt]);
                    acc[is][lt][pt] = MFMA(cf[is][lt][1], hf[pt][1], acc[is][lt][pt]);
                }
    }
    #pragma unroll
    for (int is = 0; is < 2; ++is) {
        int strip = is ? (7 - w) : w;
        #pragma unroll
        for (int lt = 0; lt < 2; ++lt) {
            float e[4];
            #pragma unroll
            for (int r = 0; r < 4; ++r)
                e[r] = __expf(sCum[strip * 32 + lt * 16 + quad * 4 + r]);
            #pragma unroll
            for (int pt = 0; pt < 4; ++pt)
                #pragma unroll
                for (int r = 0; r < 4; ++r)
                    acc[is][lt][pt][r] *= e[r];
        }
    }

    short* Pw = P_s + w * 32 * PST;

    for (int st = 0; st < 4; ++st) {
        __syncthreads();
        {
            int ss = t >> 2, q4 = (t & 3) * 16;
            size_t grow = (rowbase + st * 64 + ss) * NH + h;
            const float4* kp = (const float4*)(kst + grow * 64 + q4);
            float4 v0 = kp[0], v1 = kp[1], v2 = kp[2], v3 = kp[3];
            float ssq = v0.x*v0.x + v0.y*v0.y + v0.z*v0.z + v0.w*v0.w
                      + v1.x*v1.x + v1.y*v1.y + v1.z*v1.z + v1.w*v1.w
                      + v2.x*v2.x + v2.y*v2.y + v2.z*v2.z + v2.w*v2.w
                      + v3.x*v3.x + v3.y*v3.y + v3.z*v3.z + v3.w*v3.w;
            ssq += __shfl_xor(ssq, 1);
            ssq += __shfl_xor(ssq, 2);
            float ib = 1.f / fmaxf(sqrtf(ssq), 1e-12f);
            uint u[8];
            u[0] = packbf2(v0.x * ib, v0.y * ib); u[1] = packbf2(v0.z * ib, v0.w * ib);
            u[2] = packbf2(v1.x * ib, v1.y * ib); u[3] = packbf2(v1.z * ib, v1.w * ib);
            u[4] = packbf2(v2.x * ib, v2.y * ib); u[5] = packbf2(v2.z * ib, v2.w * ib);
            u[6] = packbf2(v3.x * ib, v3.y * ib); u[7] = packbf2(v3.z * ib, v3.w * ib);
            uint* dst = (uint*)(B_s + ss * PST + q4);
            *(uint4*)dst = make_uint4(u[0], u[1], u[2], u[3]);
            *(uint4*)(dst + 4) = make_uint4(u[4], u[5], u[6], u[7]);
        }
        {
            int ss2 = t & 31, qh = t >> 5;
            int p0 = qh * 8;
            size_t g0 = (rowbase + st * 64 + 2 * ss2) * NH + h;
            size_t g1 = g0 + NH;
            float dt0 = sDt[st * 64 + 2 * ss2];
            float dt1 = sDt[st * 64 + 2 * ss2 + 1];
            float4 a0 = *(const float4*)(vst + g0 * 64 + p0);
            float4 a1 = *(const float4*)(vst + g0 * 64 + p0 + 4);
            float4 b0 = *(const float4*)(vst + g1 * 64 + p0);
            float4 b1 = *(const float4*)(vst + g1 * 64 + p0 + 4);
            float x0[8] = {a0.x, a0.y, a0.z, a0.w, a1.x, a1.y, a1.z, a1.w};
            float x1[8] = {b0.x, b0.y, b0.z, b0.w, b1.x, b1.y, b1.z, b1.w};
            uint* xt = (uint*)XT_s;
            #pragma unroll
            for (int i = 0; i < 8; ++i)
                xt[(p0 + i) * (PST / 2) + ss2] = packbf2(x0[i] * dt0, x1[i] * dt1);
        }
        __syncthreads();

        bf16x8 xf[4][2];
        #pragma unroll
        for (int pt = 0; pt < 4; ++pt) {
            #pragma unroll
            for (int ks = 0; ks < 2; ++ks)
                xf[pt][ks] = *(const bf16x8*)(XT_s + (pt * 16 + l16) * PST + ks * 32 + quad * 8);
        }

        #pragma unroll
        for (int is = 0; is < 2; ++is) {
            int strip = is ? (7 - w) : w;
            int L0 = strip * 32;
            if (L0 + 31 < st * 64) continue;

            #pragma unroll
            for (int lt = 0; lt < 2; ++lt) {
                int Lt = L0 + lt * 16;
                float cl = sCum[Lt + l16];
                int lrow = lt * 16 + l16;
                #pragma unroll
                for (int mt = 0; mt < 4; ++mt) {
                    int S0 = st * 64 + mt * 16;
                    uint* pdst = (uint*)(Pw + lrow * PST + mt * 16 + quad * 4);
                    if (S0 > Lt + 15) {
                        *(uint2*)pdst = make_uint2(0u, 0u);
                        continue;
                    }
                    f32x4 sa = (f32x4){0.f, 0.f, 0.f, 0.f};
                    bf16x8 af0 = *(const bf16x8*)(B_s + (mt * 16 + l16) * PST + quad * 8);
                    bf16x8 af1 = *(const bf16x8*)(B_s + (mt * 16 + l16) * PST + 32 + quad * 8);
                    sa = MFMA(af0, cf[is][lt][0], sa);
                    sa = MFMA(af1, cf[is][lt][1], sa);
                    float vals[4];
                    #pragma unroll
                    for (int r = 0; r < 4; ++r) {
                        int s = S0 + quad * 4 + r;
                        float v = sa[r] * __expf(cl - sCum[s]);
                        vals[r] = (Lt + l16 >= s) ? v : 0.f;
                    }
                    *(uint2*)pdst = make_uint2(packbf2(vals[0], vals[1]),
                                               packbf2(vals[2], vals[3]));
                }
            }
            #pragma unroll
            for (int lt = 0; lt < 2; ++lt) {
                int Lmax = L0 + lt * 16 + 15;
                #pragma unroll
                for (int ks = 0; ks < 2; ++ks) {
                    if (st * 64 + ks * 32 > Lmax) continue;
                    bf16x8 af = *(const bf16x8*)(Pw + (lt * 16 + l16) * PST + ks * 32 + quad * 8);
                    #pragma unroll
                    for (int pt = 0; pt < 4; ++pt)
                        acc[is][lt][pt] = MFMA(af, xf[pt][ks], acc[is][lt][pt]);
                }
            }
        }
    }

    #pragma unroll
    for (int is = 0; is < 2; ++is) {
        int strip = is ? (7 - w) : w;
        #pragma unroll
        for (int lt = 0; lt < 2; ++lt)
            #pragma unroll
            for (int pt = 0; pt < 4; ++pt)
                #pragma unroll
                for (int r = 0; r < 4; ++r) {
                    int l = strip * 32 + lt * 16 + quad * 4 + r;
                    int p = pt * 16 + l16;
                    ygb[((rowbase + l) * NH + h) * 64 + p] = f2bf(acc[is][lt][pt][r]);
                }
    }
}

// ---------------------------------------------------------------------------
// K7: fused gate + RMSNorm + per-head o_proj.
// Block = (16 rows) x (head-half: 16 heads). Grid 512, ~34 KB LDS -> 4/CU.
// out[r,h,q] = sil[r,h]*scale[r]*(y[r,h,:] @ nwWT[h]) + o_b[h,q]
// ---------------------------------------------------------------------------
__global__ __launch_bounds__(256) void k_out(
    const short* __restrict__ ygb, const float* __restrict__ part,
    const float* __restrict__ g_b, const short* __restrict__ nwWT,
    const float* __restrict__ o_b, float* __restrict__ out)
{
    __shared__ __align__(16) short yS[16 * 1024];   // 16 rows x own head-half
    __shared__ float silS[16 * 32];
    __shared__ float scaleS[16];
    int blk = blockIdx.x;
    int half = blk & 1, rt = blk >> 1;
    int r0 = rt * 16;
    int t = threadIdx.x;
    int w = t >> 6, lane = t & 63, quad = lane >> 4, l16 = lane & 15;

    // phase 0: gates (sum g split-K partials + bias, silu) for all 32 heads
    const float* gpart = part + 4 * 131072;
    #pragma unroll
    for (int ii = 0; ii < 2; ++ii) {
        int idx = t + ii * 256;                 // (row 0..15, h 0..31)
        int rr = idx >> 5, hh = idx & 31;
        int rid = (r0 + rr) * 32 + hh;
        float g = gpart[rid] + gpart[131072 + rid] + gpart[262144 + rid]
                + gpart[393216 + rid] + g_b[hh];
        silS[idx] = g / (1.f + expf(-g));
    }
    __syncthreads();

    // phase 1: stream full rows, gated sumsq; stash own half to LDS (swizzled)
    int r = t >> 4, cl = t & 15;
    const char* yrow = (const char*)(ygb + (size_t)(r0 + r) * 2048);
    float ssq = 0.f;
    #pragma unroll
    for (int i = 0; i < 16; ++i) {
        int cb = i * 256 + cl * 16;             // byte offset 0..4095
        uint4 u = *(const uint4*)(yrow + cb);
        float s = silS[r * 32 + (cb >> 7)];
        float v0 = bf2f((ushort)(u.x & 0xFFFF)) * s, v1 = bf2f((ushort)(u.x >> 16)) * s;
        float v2 = bf2f((ushort)(u.y & 0xFFFF)) * s, v3 = bf2f((ushort)(u.y >> 16)) * s;
        float v4 = bf2f((ushort)(u.z & 0xFFFF)) * s, v5 = bf2f((ushort)(u.z >> 16)) * s;
        float v6 = bf2f((ushort)(u.w & 0xFFFF)) * s, v7 = bf2f((ushort)(u.w >> 16)) * s;
        ssq += v0*v0 + v1*v1 + v2*v2 + v3*v3 + v4*v4 + v5*v5 + v6*v6 + v7*v7;
        if ((cb >> 11) == half) {
            int cbl = cb & 2047;
            *(uint4*)((char*)yS + r * 2048 + (cbl ^ ((r & 7) << 4))) = u;
        }
    }
    ssq += __shfl_xor(ssq, 1); ssq += __shfl_xor(ssq, 2);
    ssq += __shfl_xor(ssq, 4); ssq += __shfl_xor(ssq, 8);
    if (cl == 0) scaleS[r] = rsqrtf(ssq / 2048.f + 1e-5f);
    __syncthreads();

    // phase 2: wave w handles 4 heads of its half
    #pragma unroll
    for (int hh = 0; hh < 4; ++hh) {
        int h = half * 16 + w * 4 + hh;
        int hl = h & 15;
        const short* wb = nwWT + (size_t)h * 4096;
        bf16x8 bfr[4][2];
        #pragma unroll
        for (int nt = 0; nt < 4; ++nt)
            #pragma unroll
            for (int ks = 0; ks < 2; ++ks)
                bfr[nt][ks] = *(const bf16x8*)(wb + (nt * 16 + l16) * 64 + ks * 32 + quad * 8);
        bf16x8 af[2];
        #pragma unroll
        for (int ks = 0; ks < 2; ++ks) {
            int cbl = hl * 128 + ks * 64 + quad * 16;
            af[ks] = *(const bf16x8*)((const char*)yS + l16 * 2048 + (cbl ^ ((l16 & 7) << 4)));
        }
        f32x4 acc[4];
        #pragma unroll
        for (int nt = 0; nt < 4; ++nt) acc[nt] = (f32x4){0.f, 0.f, 0.f, 0.f};
        #pragma unroll
        for (int ks = 0; ks < 2; ++ks)
            #pragma unroll
            for (int nt = 0; nt < 4; ++nt)
                acc[nt] = MFMA(af[ks], bfr[nt][ks], acc[nt]);
        #pragma unroll
        for (int nt = 0; nt < 4; ++nt) {
            float bv = o_b[h * 64 + nt * 16 + l16];
            #pragma unroll
            for (int rr = 0; rr < 4; ++rr) {
                int row = quad * 4 + rr;
                float o = acc[nt][rr] * silS[row * 32 + h] * scaleS[row] + bv;
                out[(size_t)(r0 + row) * 2048 + h * 64 + nt * 16 + l16] = o;
            }
        }
    }
}

extern "C" void kernel_launch(void* const* d_in, const int* in_sizes, int n_in,
                              void* d_out, int out_size, void* d_ws, size_t ws_size,
                              hipStream_t stream) {
    const float* hs_ab   = (const float*)d_in[0];
    const float* hs_g    = (const float*)d_in[1];
    const float* qst     = (const float*)d_in[2];
    const float* kst     = (const float*)d_in[3];
    const float* vst     = (const float*)d_in[4];
    const float* dt_w    = (const float*)d_in[5];
    const float* dt_b    = (const float*)d_in[6];
    const float* g_w     = (const float*)d_in[7];
    const float* g_b     = (const float*)d_in[8];
    const float* A_log   = (const float*)d_in[9];
    const float* dt_bias = (const float*)d_in[10];
    const float* norm_w  = (const float*)d_in[11];
    const float* o_w     = (const float*)d_in[12];
    const float* o_b     = (const float*)d_in[13];
    float* out = (float*)d_out;

    float* ws = (float*)d_ws;
    size_t off = 0;
    float* part   = ws + off; off += (size_t)2 * KSPLIT * 4096 * 32;  // 1M floats
    float* cumc   = ws + off; off += (size_t)NBCH * CHUNK;
    float* wvc    = ws + off; off += (size_t)NBCH * CHUNK;
    float* dtc    = ws + off; off += (size_t)NBCH * CHUNK;
    float* cd_ws  = ws + off; off += (size_t)NBCH;
    float* sp     = ws + off; off += (size_t)NBCH * 2 * 4096;
    float* Hp     = ws + off; off += (size_t)NBCH * 4096;
    short* nwWT   = (short*)(ws + off); off += (size_t)NH * 64 * 64 / 2;  // 131072 shorts

    short* ygb = (short*)sp;   // aliases sp (sp fully consumed by k_scan)

    k_proj<<<2 * KSPLIT * (BATCH * SEQ / 32) + NH, 256, 0, stream>>>(
        hs_ab, hs_g, dt_w, g_w, o_w, norm_w, part, nwWT);
    k_cumsum<<<NBCH, 256, 0, stream>>>(part, dt_b, dt_bias, A_log,
                                       cumc, wvc, dtc, cd_ws);
    k_states<<<NBCH * 2, 256, 0, stream>>>(kst, vst, wvc, sp);
    k_scan<<<BATCH * NH * 4096 / 256, 256, 0, stream>>>(sp, cd_ws, Hp);
    k_intra<<<NBCH, 256, 0, stream>>>(qst, kst, vst, cumc, dtc, Hp, ygb);
    k_out<<<2 * (BATCH * SEQ / 16), 256, 0, stream>>>(ygb, part, g_b, nwWT, o_b, out);
}

// Round 4
// 268.289 us; speedup vs baseline: 1.0741x; 1.0094x over previous
//
#include <hip/hip_runtime.h>
#include <math.h>

#define BATCH 2
#define SEQ   2048
#define NH    32
#define HID   2048
#define CHUNK 256
#define NCH   8
#define NBCH  (BATCH*NCH*NH)   // 512
#define PST   72               // padded bf16 LDS leading dim (b128-alignable)
#define BK    256
#define APST  264              // BK+8 shorts; row stride 528 B = 33*16 (b128-aligned)
#define KSPLIT 4
#define KSEG  (HID / KSPLIT)   // 512

typedef __attribute__((ext_vector_type(4))) float f32x4;
typedef __attribute__((ext_vector_type(8))) short bf16x8;
typedef unsigned int uint;
typedef unsigned short ushort;

__device__ __forceinline__ float softplusf(float x) {
    return x > 20.f ? x : log1pf(expf(x));
}

__device__ __forceinline__ short f2bf(float f) {
    union { float f; uint u; } v; v.f = f;
    uint r = v.u + 0x7FFF + ((v.u >> 16) & 1);
    return (short)(r >> 16);
}
__device__ __forceinline__ float bf2f(ushort s) {
    union { uint u; float f; } v; v.u = ((uint)s) << 16; return v.f;
}
__device__ __forceinline__ uint packbf2(float lo, float hi) {
    return (uint)(ushort)f2bf(lo) | ((uint)(ushort)f2bf(hi) << 16);
}

struct BF8 { union { bf16x8 v; short s[8]; }; };

__device__ __forceinline__ bf16x8 load_cvt8(const float* p, float scale) {
    float4 a = *(const float4*)p;
    float4 b = *(const float4*)(p + 4);
    BF8 r;
    r.s[0]=f2bf(a.x*scale); r.s[1]=f2bf(a.y*scale); r.s[2]=f2bf(a.z*scale); r.s[3]=f2bf(a.w*scale);
    r.s[4]=f2bf(b.x*scale); r.s[5]=f2bf(b.y*scale); r.s[6]=f2bf(b.z*scale); r.s[7]=f2bf(b.w*scale);
    return r.v;
}

__device__ __forceinline__ bf16x8 cvt8(float4 a, float4 b, float s) {
    BF8 r;
    r.s[0]=f2bf(a.x*s); r.s[1]=f2bf(a.y*s); r.s[2]=f2bf(a.z*s); r.s[3]=f2bf(a.w*s);
    r.s[4]=f2bf(b.x*s); r.s[5]=f2bf(b.y*s); r.s[6]=f2bf(b.z*s); r.s[7]=f2bf(b.w*s);
    return r.v;
}

#define MFMA(a,b,c) __builtin_amdgcn_mfma_f32_16x16x32_bf16((a),(b),(c),0,0,0)

// ---------------------------------------------------------------------------
// K1: dt/g projections as bf16 MFMA GEMM (split-K by 4), plus 32 trailing
// blocks that build nwWT[h][q][p] = bf16(o_w[h][p][q] * norm_w[h*64+p]).
// ---------------------------------------------------------------------------
__global__ __launch_bounds__(256) void k_proj(
    const float* __restrict__ hs_ab, const float* __restrict__ hs_g,
    const float* __restrict__ dt_w, const float* __restrict__ g_w,
    const float* __restrict__ o_w,  const float* __restrict__ norm_w,
    float* __restrict__ part, short* __restrict__ nwWT)
{
    __shared__ __align__(16) short As[32 * APST];
    __shared__ __align__(16) short Bs[32 * APST];
    int blk = blockIdx.x;
    int t = threadIdx.x;

    if (blk >= 2 * KSPLIT * 128) {
        // --- weight prep: transpose o_w per head, fold norm_w, cast bf16 ---
        int h = blk - 2 * KSPLIT * 128;
        float* tile = (float*)As;   // 64x64 f32 = 16 KB
        {
            int p = t >> 2, q0 = (t & 3) * 16;
            const float* wp = o_w + (size_t)h * 4096 + p * 64 + q0;
            #pragma unroll
            for (int i = 0; i < 4; ++i)
                *(float4*)(tile + p * 64 + q0 + i * 4) = *(const float4*)(wp + i * 4);
        }
        __syncthreads();
        int q = t >> 2, p0 = (t & 3) * 16;
        uint us[8];
        #pragma unroll
        for (int j = 0; j < 8; ++j) {
            float lo = tile[(p0 + 2*j    ) * 64 + q] * norm_w[h * 64 + p0 + 2*j];
            float hi = tile[(p0 + 2*j + 1) * 64 + q] * norm_w[h * 64 + p0 + 2*j + 1];
            us[j] = packbf2(lo, hi);
        }
        uint* dst = (uint*)(nwWT + (size_t)h * 4096 + q * 64 + p0);
        *(uint4*)dst       = make_uint4(us[0], us[1], us[2], us[3]);
        *(uint4*)(dst + 4) = make_uint4(us[4], us[5], us[6], us[7]);
        return;
    }

    int ksp = blk >> 8;          // 0..3 : K segment
    int rem = blk & 255;
    int which = rem >> 7;        // 0..1 : ab vs g
    int rt = rem & 127;          // 0..127 : 32-row tile
    int r0 = rt * 32;
    const float* Am = which ? hs_g : hs_ab;
    const float* W  = which ? g_w  : dt_w;
    int w = t >> 6, lane = t & 63, quad = lane >> 4, l16 = lane & 15;
    int mh = w & 1, nh = w >> 1;

    f32x4 acc = (f32x4){0.f, 0.f, 0.f, 0.f};

    for (int kc = ksp * KSEG; kc < ksp * KSEG + KSEG; kc += BK) {
        __syncthreads();
        {   // stage A: 32 rows x BK cols, bf16-packed
            int row = t >> 3, k0 = (t & 7) * 32;
            const float* src = Am + (size_t)(r0 + row) * HID + kc + k0;
            uint* dst = (uint*)(As + row * APST + k0);
            #pragma unroll
            for (int i = 0; i < 4; ++i) {
                float4 a = *(const float4*)(src + i * 8);
                float4 b = *(const float4*)(src + i * 8 + 4);
                dst[i*4+0] = packbf2(a.x, a.y); dst[i*4+1] = packbf2(a.z, a.w);
                dst[i*4+2] = packbf2(b.x, b.y); dst[i*4+3] = packbf2(b.z, b.w);
            }
        }
        if (t < 128) {   // stage W transposed: Bs[n][k] = W[kc+k][n], pair-packed
            int k2 = t * 2;
            const float* w0 = W + (size_t)(kc + k2) * NH;
            const float* w1 = w0 + NH;
            #pragma unroll
            for (int n = 0; n < 32; n += 4) {
                float4 a = *(const float4*)(w0 + n);
                float4 b = *(const float4*)(w1 + n);
                *((uint*)(Bs + (n+0) * APST + k2)) = packbf2(a.x, b.x);
                *((uint*)(Bs + (n+1) * APST + k2)) = packbf2(a.y, b.y);
                *((uint*)(Bs + (n+2) * APST + k2)) = packbf2(a.z, b.z);
                *((uint*)(Bs + (n+3) * APST + k2)) = packbf2(a.w, b.w);
            }
        }
        __syncthreads();
        #pragma unroll
        for (int ks = 0; ks < BK / 32; ++ks) {
            bf16x8 af = *(const bf16x8*)(As + (mh*16 + l16) * APST + ks*32 + quad*8);
            bf16x8 bf = *(const bf16x8*)(Bs + (nh*16 + l16) * APST + ks*32 + quad*8);
            acc = MFMA(af, bf, acc);
        }
    }

    int n = nh * 16 + l16;
    int Rb = r0 + mh * 16 + quad * 4;
    float* pd = part + ((size_t)(which * KSPLIT + ksp) * 4096 + Rb) * 32 + n;
    #pragma unroll
    for (int r = 0; r < 4; ++r)
        pd[r * 32] = acc[r];
}

// ---------------------------------------------------------------------------
// K2: per (b,c,h): sum dt split-K partials + bias + softplus, wave-shfl scan
// of dt*A; emits chunk-ordered cum/dt/w and chunk decay.
// ---------------------------------------------------------------------------
__global__ __launch_bounds__(256) void k_cumsum(
    const float* __restrict__ part, const float* __restrict__ dt_b,
    const float* __restrict__ dt_bias, const float* __restrict__ A_log,
    float* __restrict__ cumc, float* __restrict__ wvc,
    float* __restrict__ dtc, float* __restrict__ cd)
{
    __shared__ float wsum[4];
    int bch = blockIdx.x;
    int h = bch & 31, c = (bch >> 5) & 7, b = bch >> 8;
    int t = threadIdx.x;
    int w = t >> 6, lane = t & 63;
    int rid = (b * SEQ + c * CHUNK + t) * 32 + h;
    float s = part[rid] + part[131072 + rid] + part[262144 + rid] + part[393216 + rid];
    float dt_l = softplusf(s + dt_b[h] + dt_bias[h]);
    float A = -expf(A_log[h]);
    float v = dt_l * A;
    #pragma unroll
    for (int off = 1; off < 64; off <<= 1) {
        float u = __shfl_up(v, off);
        if (lane >= off) v += u;
    }
    if (lane == 63) wsum[w] = v;
    __syncthreads();
    float pre = 0.f;
    #pragma unroll
    for (int i = 0; i < 3; ++i)
        if (i < w) pre += wsum[i];
    float cum = v + pre;
    float tot = wsum[0] + wsum[1] + wsum[2] + wsum[3];
    size_t o = (size_t)bch * CHUNK + t;
    cumc[o] = cum;
    wvc[o] = expf(tot - cum) * dt_l;
    dtc[o] = dt_l;
    if (t == 255) cd[bch] = expf(tot);
}

// ---------------------------------------------------------------------------
// K4: partial chunk states (invB computed inline)
// ---------------------------------------------------------------------------
__global__ __launch_bounds__(256) void k_states(
    const float* __restrict__ kst, const float* __restrict__ vst,
    const float* __restrict__ wvc, float* __restrict__ sp)
{
    __shared__ __align__(16) float kS[64 * 64];
    __shared__ __align__(16) float xS[64 * 64];
    int blk = blockIdx.x;
    int half = blk & 1, bch = blk >> 1;
    int h = bch & 31, c = (bch >> 5) & 7, b = bch >> 8;
    int t = threadIdx.x;
    size_t rowbase = (size_t)b * SEQ + c * CHUNK + half * 128;
    int pg = (t & 15) * 4, ng = (t >> 4) * 4;
    float acc[4][4];
    #pragma unroll
    for (int i = 0; i < 4; ++i)
        #pragma unroll
        for (int j = 0; j < 4; ++j) acc[i][j] = 0.f;

    for (int tt = 0; tt < 2; ++tt) {
        int r0 = t >> 4;
        int c4 = (t & 15) * 4;
        #pragma unroll
        for (int i = 0; i < 4; ++i) {
            int row = r0 + i * 16;
            size_t grow = (rowbase + tt * 64 + row) * NH + h;
            float wv = wvc[(size_t)bch * CHUNK + half * 128 + tt * 64 + row];
            float4 kv = *(const float4*)(kst + grow * 64 + c4);
            float4 xv = *(const float4*)(vst + grow * 64 + c4);
            float ssq = kv.x*kv.x + kv.y*kv.y + kv.z*kv.z + kv.w*kv.w;
            ssq += __shfl_xor(ssq, 1); ssq += __shfl_xor(ssq, 2);
            ssq += __shfl_xor(ssq, 4); ssq += __shfl_xor(ssq, 8);
            float ib = 1.f / fmaxf(sqrtf(ssq), 1e-12f);
            *(float4*)(kS + row * 64 + c4) =
                make_float4(kv.x * ib, kv.y * ib, kv.z * ib, kv.w * ib);
            *(float4*)(xS + row * 64 + c4) =
                make_float4(xv.x * wv, xv.y * wv, xv.z * wv, xv.w * wv);
        }
        __syncthreads();
        for (int ll = 0; ll < 64; ++ll) {
            float4 x4 = *(const float4*)(xS + ll * 64 + pg);
            float4 k4 = *(const float4*)(kS + ll * 64 + ng);
            acc[0][0] += x4.x * k4.x; acc[0][1] += x4.x * k4.y;
            acc[0][2] += x4.x * k4.z; acc[0][3] += x4.x * k4.w;
            acc[1][0] += x4.y * k4.x; acc[1][1] += x4.y * k4.y;
            acc[1][2] += x4.y * k4.z; acc[1][3] += x4.y * k4.w;
            acc[2][0] += x4.z * k4.x; acc[2][1] += x4.z * k4.y;
            acc[2][2] += x4.z * k4.z; acc[2][3] += x4.z * k4.w;
            acc[3][0] += x4.w * k4.x; acc[3][1] += x4.w * k4.y;
            acc[3][2] += x4.w * k4.z; acc[3][3] += x4.w * k4.w;
        }
        __syncthreads();
    }
    size_t obase = (size_t)blk * 4096;
    #pragma unroll
    for (int i = 0; i < 4; ++i)
        *(float4*)(sp + obase + (pg + i) * 64 + ng) =
            make_float4(acc[i][0], acc[i][1], acc[i][2], acc[i][3]);
}

// ---------------------------------------------------------------------------
// K5: inter-chunk scan
// ---------------------------------------------------------------------------
__global__ __launch_bounds__(256) void k_scan(
    const float* __restrict__ sp, const float* __restrict__ cd,
    float* __restrict__ Hp)
{
    size_t id = (size_t)blockIdx.x * 256 + threadIdx.x;
    size_t bh = id >> 12, pn = id & 4095;
    size_t b = bh >> 5, h = bh & 31;
    float carry = 0.f;
    for (int c = 0; c < NCH; ++c) {
        size_t bch = (b * NCH + c) * NH + h;
        float st = sp[(bch * 2) * 4096 + pn] + sp[(bch * 2 + 1) * 4096 + pn];
        Hp[bch * 4096 + pn] = carry;
        carry = cd[bch] * carry + st;
    }
}

// ---------------------------------------------------------------------------
// K6: MFMA intra-chunk + H_prev. R4: latency-bound fix —
//  (a) register-prefetch next st's k/v global loads (issued before pack,
//      consumed next iteration -> HBM latency hides under P/PV compute);
//  (b) double-buffered B_s/XT_s -> ONE barrier per st iteration (was 2).
//      Write buf[st&1] pre-barrier; reads of buf[n]@st-2 are separated from
//      the next write@st by barrier(st-1) (+ __syncthreads' lgkm drain).
//  LDS 56 KB -> still 2 blocks/CU; st loop fully unrolled so prefetch regs
//  are statically indexed (no scratch).
// ---------------------------------------------------------------------------
__global__ __launch_bounds__(256, 2) void k_intra(
    const float* __restrict__ qst, const float* __restrict__ kst,
    const float* __restrict__ vst,
    const float* __restrict__ cumc, const float* __restrict__ dtc,
    const float* __restrict__ Hp,
    short* __restrict__ ygb)
{
    __shared__ __align__(16) short B_s[2][64 * PST];
    __shared__ __align__(16) short XT_s[2][64 * PST];
    __shared__ __align__(16) short P_s[4 * 32 * PST];
    __shared__ float sCum[256];
    __shared__ float sDt[256];

    int bch = blockIdx.x;
    int h = bch & 31, c = (bch >> 5) & 7, b = bch >> 8;
    int t = threadIdx.x;
    int w = t >> 6, lane = t & 63;
    int quad = lane >> 4, l16 = lane & 15;
    size_t rowbase = (size_t)b * SEQ + c * CHUNK;

    sCum[t] = cumc[(size_t)bch * CHUNK + t];
    sDt[t]  = dtc[(size_t)bch * CHUNK + t];

    // staging thread mapping (constant across st)
    int ssA = t >> 2, q4A = (t & 3) * 16;      // B_s: row ssA, 16-col group
    int ss2 = t & 31, p0 = (t >> 5) * 8;       // XT: rows 2*ss2(+1), 8 p's

    // prefetch k/v for st=0 (flies under the Q/Hp prologue)
    float4 kv[4], xa[2], xb[2];
    {
        size_t gK = (rowbase + ssA) * NH + h;
        const float4* kp = (const float4*)(kst + gK * 64 + q4A);
        kv[0] = kp[0]; kv[1] = kp[1]; kv[2] = kp[2]; kv[3] = kp[3];
        size_t g0 = (rowbase + 2 * ss2) * NH + h;
        const float* vp0 = vst + g0 * 64 + p0;
        const float* vp1 = vst + (g0 + NH) * 64 + p0;
        xa[0] = *(const float4*)vp0; xa[1] = *(const float4*)(vp0 + 4);
        xb[0] = *(const float4*)vp1; xb[1] = *(const float4*)(vp1 + 4);
    }

    bf16x8 cf[2][2][2];
    #pragma unroll
    for (int is = 0; is < 2; ++is) {
        int strip = is ? (7 - w) : w;
        #pragma unroll
        for (int lt = 0; lt < 2; ++lt) {
            int l = strip * 32 + lt * 16 + l16;
            size_t grow = (rowbase + l) * NH + h;
            const float* qp = qst + grow * 64 + quad * 8;
            float4 a  = *(const float4*)qp;
            float4 bq = *(const float4*)(qp + 4);
            float4 c2 = *(const float4*)(qp + 32);
            float4 d  = *(const float4*)(qp + 36);
            float ssq = a.x*a.x + a.y*a.y + a.z*a.z + a.w*a.w
                      + bq.x*bq.x + bq.y*bq.y + bq.z*bq.z + bq.w*bq.w
                      + c2.x*c2.x + c2.y*c2.y + c2.z*c2.z + c2.w*c2.w
                      + d.x*d.x + d.y*d.y + d.z*d.z + d.w*d.w;
            ssq += __shfl_xor(ssq, 16);
            ssq += __shfl_xor(ssq, 32);
            float ic = 1.f / fmaxf(sqrtf(ssq), 1e-12f);
            cf[is][lt][0] = cvt8(a, bq, ic);
            cf[is][lt][1] = cvt8(c2, d, ic);
        }
    }

    f32x4 acc[2][2][4];
    #pragma unroll
    for (int is = 0; is < 2; ++is)
        #pragma unroll
        for (int lt = 0; lt < 2; ++lt)
            #pragma unroll
            for (int pt = 0; pt < 4; ++pt)
                acc[is][lt][pt] = (f32x4){0.f, 0.f, 0.f, 0.f};

    {
        bf16x8 hf[4][2];
        #pragma unroll
        for (int pt = 0; pt < 4; ++pt) {
            const float* hp = Hp + (size_t)bch * 4096 + (pt * 16 + l16) * 64 + quad * 8;
            hf[pt][0] = load_cvt8(hp, 1.f);
            hf[pt][1] = load_cvt8(hp + 32, 1.f);
        }
        #pragma unroll
        for (int is = 0; is < 2; ++is)
            #pragma unroll
            for (int lt = 0; lt < 2; ++lt)
                #pragma unroll
                for (int pt = 0; pt < 4; ++pt) {
                    acc[is][lt][pt] = MFMA(cf[is][lt][0], hf[pt][0], acc[is][lt][pt]);
                    acc[is][lt][pt] = MFMA(cf[is][lt][1], hf[pt][1], acc[is][lt][pt]);
                }
    }
    __syncthreads();   // sCum/sDt now visible to all waves
    #pragma unroll
    for (int is = 0; is < 2; ++is) {
        int strip = is ? (7 - w) : w;
        #pragma unroll
        for (int lt = 0; lt < 2; ++lt) {
            float e[4];
            #pragma unroll
            for (int r = 0; r < 4; ++r)
                e[r] = __expf(sCum[strip * 32 + lt * 16 + quad * 4 + r]);
            #pragma unroll
            for (int pt = 0; pt < 4; ++pt)
                #pragma unroll
                for (int r = 0; r < 4; ++r)
                    acc[is][lt][pt][r] *= e[r];
        }
    }

    short* Pw = P_s + w * 32 * PST;

    #pragma unroll
    for (int st = 0; st < 4; ++st) {
        // issue next-tile global loads first (hide under pack+barrier+compute)
        float4 kvN[4], xaN[2], xbN[2];
        if (st < 3) {
            size_t gK = (rowbase + (st + 1) * 64 + ssA) * NH + h;
            const float4* kp = (const float4*)(kst + gK * 64 + q4A);
            kvN[0] = kp[0]; kvN[1] = kp[1]; kvN[2] = kp[2]; kvN[3] = kp[3];
            size_t g0 = (rowbase + (st + 1) * 64 + 2 * ss2) * NH + h;
            const float* vp0 = vst + g0 * 64 + p0;
            const float* vp1 = vst + (g0 + NH) * 64 + p0;
            xaN[0] = *(const float4*)vp0; xaN[1] = *(const float4*)(vp0 + 4);
            xbN[0] = *(const float4*)vp1; xbN[1] = *(const float4*)(vp1 + 4);
        }

        short* Bb = B_s[st & 1];
        short* Xb = XT_s[st & 1];
        {   // pack K-hat (bf16) into Bb from regs
            float ssq = kv[0].x*kv[0].x + kv[0].y*kv[0].y + kv[0].z*kv[0].z + kv[0].w*kv[0].w
                      + kv[1].x*kv[1].x + kv[1].y*kv[1].y + kv[1].z*kv[1].z + kv[1].w*kv[1].w
                      + kv[2].x*kv[2].x + kv[2].y*kv[2].y + kv[2].z*kv[2].z + kv[2].w*kv[2].w
                      + kv[3].x*kv[3].x + kv[3].y*kv[3].y + kv[3].z*kv[3].z + kv[3].w*kv[3].w;
            ssq += __shfl_xor(ssq, 1);
            ssq += __shfl_xor(ssq, 2);
            float ib = 1.f / fmaxf(sqrtf(ssq), 1e-12f);
            uint u[8];
            u[0] = packbf2(kv[0].x * ib, kv[0].y * ib); u[1] = packbf2(kv[0].z * ib, kv[0].w * ib);
            u[2] = packbf2(kv[1].x * ib, kv[1].y * ib); u[3] = packbf2(kv[1].z * ib, kv[1].w * ib);
            u[4] = packbf2(kv[2].x * ib, kv[2].y * ib); u[5] = packbf2(kv[2].z * ib, kv[2].w * ib);
            u[6] = packbf2(kv[3].x * ib, kv[3].y * ib); u[7] = packbf2(kv[3].z * ib, kv[3].w * ib);
            uint* dst = (uint*)(Bb + ssA * PST + q4A);
            *(uint4*)dst = make_uint4(u[0], u[1], u[2], u[3]);
            *(uint4*)(dst + 4) = make_uint4(u[4], u[5], u[6], u[7]);
        }
        {   // pack dt-scaled X^T (bf16 pair-packed) into Xb from regs
            float dt0 = sDt[st * 64 + 2 * ss2];
            float dt1 = sDt[st * 64 + 2 * ss2 + 1];
            float x0[8] = {xa[0].x, xa[0].y, xa[0].z, xa[0].w,
                           xa[1].x, xa[1].y, xa[1].z, xa[1].w};
            float x1[8] = {xb[0].x, xb[0].y, xb[0].z, xb[0].w,
                           xb[1].x, xb[1].y, xb[1].z, xb[1].w};
            uint* xt = (uint*)Xb;
            #pragma unroll
            for (int i = 0; i < 8; ++i)
                xt[(p0 + i) * (PST / 2) + ss2] = packbf2(x0[i] * dt0, x1[i] * dt1);
        }
        __syncthreads();

        bf16x8 xf[4][2];
        #pragma unroll
        for (int pt = 0; pt < 4; ++pt) {
            #pragma unroll
            for (int ks = 0; ks < 2; ++ks)
                xf[pt][ks] = *(const bf16x8*)(Xb + (pt * 16 + l16) * PST + ks * 32 + quad * 8);
        }

        #pragma unroll
        for (int is = 0; is < 2; ++is) {
            int strip = is ? (7 - w) : w;
            int L0 = strip * 32;
            if (L0 + 31 < st * 64) continue;

            #pragma unroll
            for (int lt = 0; lt < 2; ++lt) {
                int Lt = L0 + lt * 16;
                float cl = sCum[Lt + l16];
                int lrow = lt * 16 + l16;
                #pragma unroll
                for (int mt = 0; mt < 4; ++mt) {
                    int S0 = st * 64 + mt * 16;
                    uint* pdst = (uint*)(Pw + lrow * PST + mt * 16 + quad * 4);
                    if (S0 > Lt + 15) {
                        *(uint2*)pdst = make_uint2(0u, 0u);
                        continue;
                    }
                    f32x4 sa = (f32x4){0.f, 0.f, 0.f, 0.f};
                    bf16x8 af0 = *(const bf16x8*)(Bb + (mt * 16 + l16) * PST + quad * 8);
                    bf16x8 af1 = *(const bf16x8*)(Bb + (mt * 16 + l16) * PST + 32 + quad * 8);
                    sa = MFMA(af0, cf[is][lt][0], sa);
                    sa = MFMA(af1, cf[is][lt][1], sa);
                    float vals[4];
                    #pragma unroll
                    for (int r = 0; r < 4; ++r) {
                        int s = S0 + quad * 4 + r;
                        float v = sa[r] * __expf(cl - sCum[s]);
                        vals[r] = (Lt + l16 >= s) ? v : 0.f;
                    }
                    *(uint2*)pdst = make_uint2(packbf2(vals[0], vals[1]),
                                               packbf2(vals[2], vals[3]));
                }
            }
            #pragma unroll
            for (int lt = 0; lt < 2; ++lt) {
                int Lmax = L0 + lt * 16 + 15;
                #pragma unroll
                for (int ks = 0; ks < 2; ++ks) {
                    if (st * 64 + ks * 32 > Lmax) continue;
                    bf16x8 af = *(const bf16x8*)(Pw + (lt * 16 + l16) * PST + ks * 32 + quad * 8);
                    #pragma unroll
                    for (int pt = 0; pt < 4; ++pt)
                        acc[is][lt][pt] = MFMA(af, xf[pt][ks], acc[is][lt][pt]);
                }
            }
        }

        if (st < 3) {
            kv[0] = kvN[0]; kv[1] = kvN[1]; kv[2] = kvN[2]; kv[3] = kvN[3];
            xa[0] = xaN[0]; xa[1] = xaN[1];
            xb[0] = xbN[0]; xb[1] = xbN[1];
        }
    }

    #pragma unroll
    for (int is = 0; is < 2; ++is) {
        int strip = is ? (7 - w) : w;
        #pragma unroll
        for (int lt = 0; lt < 2; ++lt)
            #pragma unroll
            for (int pt = 0; pt < 4; ++pt)
                #pragma unroll
                for (int r = 0; r < 4; ++r) {
                    int l = strip * 32 + lt * 16 + quad * 4 + r;
                    int p = pt * 16 + l16;
                    ygb[((rowbase + l) * NH + h) * 64 + p] = f2bf(acc[is][lt][pt][r]);
                }
    }
}

// ---------------------------------------------------------------------------
// K7: fused gate + RMSNorm + per-head o_proj.
// ---------------------------------------------------------------------------
__global__ __launch_bounds__(256) void k_out(
    const short* __restrict__ ygb, const float* __restrict__ part,
    const float* __restrict__ g_b, const short* __restrict__ nwWT,
    const float* __restrict__ o_b, float* __restrict__ out)
{
    __shared__ __align__(16) short yS[16 * 1024];   // 16 rows x own head-half
    __shared__ float silS[16 * 32];
    __shared__ float scaleS[16];
    int blk = blockIdx.x;
    int half = blk & 1, rt = blk >> 1;
    int r0 = rt * 16;
    int t = threadIdx.x;
    int w = t >> 6, lane = t & 63, quad = lane >> 4, l16 = lane & 15;

    // phase 0: gates (sum g split-K partials + bias, silu) for all 32 heads
    const float* gpart = part + 4 * 131072;
    #pragma unroll
    for (int ii = 0; ii < 2; ++ii) {
        int idx = t + ii * 256;                 // (row 0..15, h 0..31)
        int rr = idx >> 5, hh = idx & 31;
        int rid = (r0 + rr) * 32 + hh;
        float g = gpart[rid] + gpart[131072 + rid] + gpart[262144 + rid]
                + gpart[393216 + rid] + g_b[hh];
        silS[idx] = g / (1.f + expf(-g));
    }
    __syncthreads();

    // phase 1: stream full rows, gated sumsq; stash own half to LDS (swizzled)
    int r = t >> 4, cl = t & 15;
    const char* yrow = (const char*)(ygb + (size_t)(r0 + r) * 2048);
    float ssq = 0.f;
    #pragma unroll
    for (int i = 0; i < 16; ++i) {
        int cb = i * 256 + cl * 16;             // byte offset 0..4095
        uint4 u = *(const uint4*)(yrow + cb);
        float s = silS[r * 32 + (cb >> 7)];
        float v0 = bf2f((ushort)(u.x & 0xFFFF)) * s, v1 = bf2f((ushort)(u.x >> 16)) * s;
        float v2 = bf2f((ushort)(u.y & 0xFFFF)) * s, v3 = bf2f((ushort)(u.y >> 16)) * s;
        float v4 = bf2f((ushort)(u.z & 0xFFFF)) * s, v5 = bf2f((ushort)(u.z >> 16)) * s;
        float v6 = bf2f((ushort)(u.w & 0xFFFF)) * s, v7 = bf2f((ushort)(u.w >> 16)) * s;
        ssq += v0*v0 + v1*v1 + v2*v2 + v3*v3 + v4*v4 + v5*v5 + v6*v6 + v7*v7;
        if ((cb >> 11) == half) {
            int cbl = cb & 2047;
            *(uint4*)((char*)yS + r * 2048 + (cbl ^ ((r & 7) << 4))) = u;
        }
    }
    ssq += __shfl_xor(ssq, 1); ssq += __shfl_xor(ssq, 2);
    ssq += __shfl_xor(ssq, 4); ssq += __shfl_xor(ssq, 8);
    if (cl == 0) scaleS[r] = rsqrtf(ssq / 2048.f + 1e-5f);
    __syncthreads();

    // phase 2: wave w handles 4 heads of its half
    #pragma unroll
    for (int hh = 0; hh < 4; ++hh) {
        int h = half * 16 + w * 4 + hh;
        int hl = h & 15;
        const short* wb = nwWT + (size_t)h * 4096;
        bf16x8 bfr[4][2];
        #pragma unroll
        for (int nt = 0; nt < 4; ++nt)
            #pragma unroll
            for (int ks = 0; ks < 2; ++ks)
                bfr[nt][ks] = *(const bf16x8*)(wb + (nt * 16 + l16) * 64 + ks * 32 + quad * 8);
        bf16x8 af[2];
        #pragma unroll
        for (int ks = 0; ks < 2; ++ks) {
            int cbl = hl * 128 + ks * 64 + quad * 16;
            af[ks] = *(const bf16x8*)((const char*)yS + l16 * 2048 + (cbl ^ ((l16 & 7) << 4)));
        }
        f32x4 acc[4];
        #pragma unroll
        for (int nt = 0; nt < 4; ++nt) acc[nt] = (f32x4){0.f, 0.f, 0.f, 0.f};
        #pragma unroll
        for (int ks = 0; ks < 2; ++ks)
            #pragma unroll
            for (int nt = 0; nt < 4; ++nt)
                acc[nt] = MFMA(af[ks], bfr[nt][ks], acc[nt]);
        #pragma unroll
        for (int nt = 0; nt < 4; ++nt) {
            float bv = o_b[h * 64 + nt * 16 + l16];
            #pragma unroll
            for (int rr = 0; rr < 4; ++rr) {
                int row = quad * 4 + rr;
                float o = acc[nt][rr] * silS[row * 32 + h] * scaleS[row] + bv;
                out[(size_t)(r0 + row) * 2048 + h * 64 + nt * 16 + l16] = o;
            }
        }
    }
}

extern "C" void kernel_launch(void* const* d_in, const int* in_sizes, int n_in,
                              void* d_out, int out_size, void* d_ws, size_t ws_size,
                              hipStream_t stream) {
    const float* hs_ab   = (const float*)d_in[0];
    const float* hs_g    = (const float*)d_in[1];
    const float* qst     = (const float*)d_in[2];
    const float* kst     = (const float*)d_in[3];
    const float* vst     = (const float*)d_in[4];
    const float* dt_w    = (const float*)d_in[5];
    const float* dt_b    = (const float*)d_in[6];
    const float* g_w     = (const float*)d_in[7];
    const float* g_b     = (const float*)d_in[8];
    const float* A_log   = (const float*)d_in[9];
    const float* dt_bias = (const float*)d_in[10];
    const float* norm_w  = (const float*)d_in[11];
    const float* o_w     = (const float*)d_in[12];
    const float* o_b     = (const float*)d_in[13];
    float* out = (float*)d_out;

    float* ws = (float*)d_ws;
    size_t off = 0;
    float* part   = ws + off; off += (size_t)2 * KSPLIT * 4096 * 32;  // 1M floats
    float* cumc   = ws + off; off += (size_t)NBCH * CHUNK;
    float* wvc    = ws + off; off += (size_t)NBCH * CHUNK;
    float* dtc    = ws + off; off += (size_t)NBCH * CHUNK;
    float* cd_ws  = ws + off; off += (size_t)NBCH;
    float* sp     = ws + off; off += (size_t)NBCH * 2 * 4096;
    float* Hp     = ws + off; off += (size_t)NBCH * 4096;
    short* nwWT   = (short*)(ws + off); off += (size_t)NH * 64 * 64 / 2;  // 131072 shorts

    short* ygb = (short*)sp;   // aliases sp (sp fully consumed by k_scan)

    k_proj<<<2 * KSPLIT * (BATCH * SEQ / 32) + NH, 256, 0, stream>>>(
        hs_ab, hs_g, dt_w, g_w, o_w, norm_w, part, nwWT);
    k_cumsum<<<NBCH, 256, 0, stream>>>(part, dt_b, dt_bias, A_log,
                                       cumc, wvc, dtc, cd_ws);
    k_states<<<NBCH * 2, 256, 0, stream>>>(kst, vst, wvc, sp);
    k_scan<<<BATCH * NH * 4096 / 256, 256, 0, stream>>>(sp, cd_ws, Hp);
    k_intra<<<NBCH, 256, 0, stream>>>(qst, kst, vst, cumc, dtc, Hp, ygb);
    k_out<<<2 * (BATCH * SEQ / 16), 256, 0, stream>>>(ygb, part, g_b, nwWT, o_b, out);
}